// Round 2
// baseline (743.431 us; speedup 1.0000x reference)
//
#include <hip/hip_runtime.h>

typedef unsigned short u16;
typedef unsigned int u32;
typedef __attribute__((ext_vector_type(8))) __bf16 bf16x8;
typedef __attribute__((ext_vector_type(4))) float f32x4;

#define E_TILE 64
#define KP 160      // padded K: 128 h + 1 bias-one + 31 zeros
#define KL 168      // LDS row stride in u16 (336B -> 2-way bank alias only)
#define EAS 56      // ea LDS row stride in u16 (112B, 16B-aligned rows, 2-way)
#define NCHUNK 64   // W2T rows staged per LDS chunk
#define WNTOT 2304
#define CST 68      // coef table stride in f32 (272B, 16B-aligned rows)

#define A0C   0.14433756729740643f   /* sqrt(1/48) */
#define A0IS3 0.08333333333333333f   /* A0/sqrt(3) = 1/12 */
#define A1IS3 0.14433756729740643f   /* (1/4)/sqrt(3) */

__device__ inline u16 f2bf(float f) {
    union { float f; u32 u; } v; v.f = f;
    u32 u = v.u;
    return (u16)((u + 0x7FFFu + ((u >> 16) & 1u)) >> 16);  // RNE
}

// W2T[n][k] bf16 (k<128: W2[k][n], k==128: b2[n], else 0)  +  W1T[n][k]=W1[k][n]
__global__ void prep_w(const float* __restrict__ w2, const float* __restrict__ b2,
                       const float* __restrict__ w1,
                       u16* __restrict__ w2t, u16* __restrict__ w1t) {
    int idx = blockIdx.x * 256 + threadIdx.x;
    const int tot2 = WNTOT * KP;
    if (idx < tot2) {
        int n = idx / KP, k = idx - n * KP;
        float v = 0.f;
        if (k < 128) v = w2[k * WNTOT + n];
        else if (k == 128) v = b2[n];
        w2t[idx] = f2bf(v);
    } else {
        int j = idx - tot2;
        if (j < 128 * 32) {
            int n = j >> 5, k = j & 31;
            w1t[j] = f2bf(w1[k * 128 + n]);
        }
    }
}

__global__ void count_k(const int* __restrict__ src, int E, int* __restrict__ cnt) {
    int i = blockIdx.x * 256 + threadIdx.x;
    if (i < E) atomicAdd(&cnt[src[i]], 1);
}

__global__ void finalize_k(float* __restrict__ out, const int* __restrict__ cnt, int total) {
    int i = blockIdx.x * 256 + threadIdx.x;
    if (i >= total) return;
    float c = (float)cnt[i / 80];
    out[i] /= fmaxf(c, 1.0f);
}

__global__ __launch_bounds__(256, 2)
void tpcl_main(const float* __restrict__ node_attr,
               const int* __restrict__ edge_index,
               const float* __restrict__ edge_attr,
               const float* __restrict__ edge_sh,
               const u16* __restrict__ w1t,
               const float* __restrict__ fc_b1,
               const u16* __restrict__ w2t,
               float* __restrict__ out,
               int N, int E)
{
    __shared__ u16 h_lds[E_TILE][KL];     // A: h (bf16), K-padded to 160
    __shared__ u16 w2_lds[NCHUNK][KL];    // B chunk (reused for ea staging in phase 0/1)
    __shared__ float coef[128 * CST];     // transposed f32 coef tables [row][edge]
                                          // rows: 0..31 L1, 32..63 X0, 64..111 X1, 112..127 L4
    __shared__ float SHs[E_TILE][4];
    __shared__ int SRCs[E_TILE];

    const int tid = threadIdx.x;
    const int ebase = blockIdx.x * E_TILE;
    const int lane = tid & 63;
    const int wave = tid >> 6;

    // ---- Phase 0: stage edge_attr tile (bf16) into w2_lds area ----
    u16* ea_lds = &w2_lds[0][0];          // 64*56 u16 = 7 KB, fits
    for (int i = tid; i < E_TILE * 32; i += 256) {
        int e = i >> 5, c = i & 31;
        int eg = ebase + e;
        float v = (eg < E) ? edge_attr[(size_t)eg * 32 + c] : 0.f;
        ea_lds[e * EAS + c] = f2bf(v);
    }

    // ---- Phase 0b: gather node_attr[dst], build transposed f32 coef tables ----
    {
        int e = tid >> 2, t4 = tid & 3;   // 4 threads per edge
        int eg = ebase + e;
        bool valid = eg < E;
        int srci = 0, dst = 0;
        float sh0 = 0.f, s1a = 0.f, s1b = 0.f, s1c = 0.f;
        if (valid) {
            srci = edge_index[eg];
            dst  = edge_index[E + eg];
            sh0  = edge_sh[(size_t)eg * 4 + 0];
            s1a  = edge_sh[(size_t)eg * 4 + 1];
            s1b  = edge_sh[(size_t)eg * 4 + 2];
            s1c  = edge_sh[(size_t)eg * 4 + 3];
        }
        if (t4 == 0) {
            SRCs[e] = srci;
            SHs[e][0] = A1IS3 * s1a;
            SHs[e][1] = A1IS3 * s1b;
            SHs[e][2] = A1IS3 * s1c;
            SHs[e][3] = A1IS3 * sh0;
        }
        const float* na = node_attr + (size_t)dst * 80;
        float l1c = A0C * sh0;
        // u = q*4 + t4 permutation keeps writes bank-conflict-free at stride CST
#pragma unroll
        for (int q = 0; q < 8; ++q) {
            int u = q * 4 + t4;
            float x = valid ? na[u] : 0.f;
            coef[u * CST + e]        = l1c * x;   // L1
            coef[(32 + u) * CST + e] = x;         // X0
        }
#pragma unroll
        for (int q = 0; q < 4; ++q) {
            int u = q * 4 + t4;
            float xa = valid ? na[32 + u * 3 + 0] : 0.f;
            float xb = valid ? na[32 + u * 3 + 1] : 0.f;
            float xc = valid ? na[32 + u * 3 + 2] : 0.f;
            coef[(64 + u * 3 + 0) * CST + e] = xa;
            coef[(64 + u * 3 + 1) * CST + e] = xb;
            coef[(64 + u * 3 + 2) * CST + e] = xc;
            coef[(112 + u) * CST + e] = A0IS3 * (xa * s1a + xb * s1b + xc * s1c);
        }
    }
    __syncthreads();

    // ---- Phase 1: h = relu(ea @ W1 + b1) via MFMA; wave = M-tile ----
    {
        int erow = wave * 16 + (lane & 15);
        int ko1 = (lane >> 4) * 8;
        bf16x8 ea_frag = *(const bf16x8*)&ea_lds[erow * EAS + ko1];
        int r0 = wave * 16 + (lane >> 4) * 4;
#pragma unroll
        for (int nt = 0; nt < 8; ++nt) {
            int ncol = nt * 16 + (lane & 15);
            bf16x8 bfr = *(const bf16x8*)&w1t[(size_t)ncol * 32 + ko1];
            f32x4 acc = {0.f, 0.f, 0.f, 0.f};
            acc = __builtin_amdgcn_mfma_f32_16x16x32_bf16(ea_frag, bfr, acc, 0, 0, 0);
            float b = fc_b1[ncol];
#pragma unroll
            for (int r = 0; r < 4; ++r)
                h_lds[r0 + r][ncol] = f2bf(fmaxf(acc[r] + b, 0.f));
        }
        // K-pad: k=128 -> 1.0 (bias row), 129..159 -> 0
        for (int i = tid; i < E_TILE * 32; i += 256) {
            int e = i >> 5, k = 128 + (i & 31);
            h_lds[e][k] = (k == 128) ? (u16)0x3F80 : (u16)0;
        }
    }
    __syncthreads();

    // ---- A fragments (2 M-frags per wave), reused across ALL N-tiles ----
    const int mw = wave >> 1, nw = wave & 1;   // 2x2 wave grid
    const int ko = (lane >> 4) * 8;
    bf16x8 afrag[2][5];
#pragma unroll
    for (int m = 0; m < 2; ++m) {
        int mrow = mw * 32 + m * 16 + (lane & 15);
#pragma unroll
        for (int kk = 0; kk < 5; ++kk)
            afrag[m][kk] = *(const bf16x8*)&h_lds[mrow][kk * 32 + ko];
    }

    float o0a[2][4] = {};    // out0[v]      [m][r]
    float o0b[2][4] = {};    // out0[16+v]   [m][r]
    float q2[2][4]  = {};
    float q3[3][2][4] = {};
    const int eg4 = (lane >> 4) * 4;

    // ---- Phase 2: 36 chunks x (2 N-tiles x 2 M-frags) x 5 K-steps ----
    for (int ch = 0; ch < 36; ++ch) {
        __syncthreads();
        {   // stage 64 W2T rows (160 u16 each)
            int nb = ch * NCHUNK;
            for (int i = tid; i < NCHUNK * 20; i += 256) {
                int r = i / 20, c = i - r * 20;
                uint4 v = *(const uint4*)&w2t[(size_t)(nb + r) * KP + c * 8];
                *(uint4*)&w2_lds[r][c * 8] = v;
            }
        }
        __syncthreads();

#pragma unroll
        for (int j = 0; j < 2; ++j) {
            int nt = nw * 2 + j;
            int nrow = nt * 16 + (lane & 15);
            f32x4 acc0 = {0.f, 0.f, 0.f, 0.f};
            f32x4 acc1 = {0.f, 0.f, 0.f, 0.f};
#pragma unroll
            for (int kk = 0; kk < 5; ++kk) {   // B-frag shared by both M-frags
                bf16x8 bfr = *(const bf16x8*)&w2_lds[nrow][kk * 32 + ko];
                acc0 = __builtin_amdgcn_mfma_f32_16x16x32_bf16(afrag[0][kk], bfr, acc0, 0, 0, 0);
                acc1 = __builtin_amdgcn_mfma_f32_16x16x32_bf16(afrag[1][kk], bfr, acc1, 0, 0, 0);
            }
            const int gnt = ch * 4 + nt;
#pragma unroll
            for (int m = 0; m < 2; ++m) {
                const f32x4 acc = m ? acc1 : acc0;
                const int e0 = mw * 32 + m * 16 + eg4;
                if (gnt < 64) {                  // w1 block, coeff L1
                    int u = gnt >> 1;
                    f32x4 cv = *(const f32x4*)&coef[u * CST + e0];
                    if (gnt & 1) {
#pragma unroll
                        for (int r = 0; r < 4; ++r) o0b[m][r] += cv[r] * acc[r];
                    } else {
#pragma unroll
                        for (int r = 0; r < 4; ++r) o0a[m][r] += cv[r] * acc[r];
                    }
                } else if (gnt < 96) {           // w2 block, coeff x0
                    int u = gnt - 64;
                    f32x4 cv = *(const f32x4*)&coef[(32 + u) * CST + e0];
#pragma unroll
                    for (int r = 0; r < 4; ++r) q2[m][r] += cv[r] * acc[r];
                } else if (gnt < 112) {          // w3 block, coeff x1[u][mm]
                    int u = gnt - 96;
                    f32x4 c0 = *(const f32x4*)&coef[(64 + u * 3 + 0) * CST + e0];
                    f32x4 c1 = *(const f32x4*)&coef[(64 + u * 3 + 1) * CST + e0];
                    f32x4 c2 = *(const f32x4*)&coef[(64 + u * 3 + 2) * CST + e0];
#pragma unroll
                    for (int r = 0; r < 4; ++r) {
                        float a = acc[r];
                        q3[0][m][r] += c0[r] * a;
                        q3[1][m][r] += c1[r] * a;
                        q3[2][m][r] += c2[r] * a;
                    }
                } else {                         // w4 block, coeff L4
                    int idx = gnt - 112;
                    int u = idx >> 1;
                    f32x4 cv = *(const f32x4*)&coef[(112 + u) * CST + e0];
                    if (idx & 1) {
#pragma unroll
                        for (int r = 0; r < 4; ++r) o0b[m][r] += cv[r] * acc[r];
                    } else {
#pragma unroll
                        for (int r = 0; r < 4; ++r) o0a[m][r] += cv[r] * acc[r];
                    }
                }
            }
        }
    }

    // ---- Phase 3: atomic scatter by edge_src ----
    {
        int v = lane & 15;
#pragma unroll
        for (int m = 0; m < 2; ++m) {
#pragma unroll
            for (int r = 0; r < 4; ++r) {
                int e = mw * 32 + m * 16 + eg4 + r;
                int eg = ebase + e;
                if (eg < E) {
                    int s = SRCs[e];
                    float* op = out + (size_t)s * 80;
                    float s0 = SHs[e][0], s1 = SHs[e][1], s2 = SHs[e][2], g = SHs[e][3];
                    unsafeAtomicAdd(&op[v],      o0a[m][r]);
                    unsafeAtomicAdd(&op[16 + v], o0b[m][r]);
                    unsafeAtomicAdd(&op[32 + v * 3 + 0], q2[m][r] * s0 + g * q3[0][m][r]);
                    unsafeAtomicAdd(&op[32 + v * 3 + 1], q2[m][r] * s1 + g * q3[1][m][r]);
                    unsafeAtomicAdd(&op[32 + v * 3 + 2], q2[m][r] * s2 + g * q3[2][m][r]);
                }
            }
        }
    }
}

extern "C" void kernel_launch(void* const* d_in, const int* in_sizes, int n_in,
                              void* d_out, int out_size, void* d_ws, size_t ws_size,
                              hipStream_t stream) {
    const float* node_attr  = (const float*)d_in[0];
    const int*   edge_index = (const int*)d_in[1];
    const float* edge_attr  = (const float*)d_in[2];
    const float* edge_sh    = (const float*)d_in[3];
    const float* fc_w1      = (const float*)d_in[4];
    const float* fc_b1      = (const float*)d_in[5];
    const float* fc_w2      = (const float*)d_in[6];
    const float* fc_b2      = (const float*)d_in[7];
    int N = in_sizes[0] / 80;
    int E = in_sizes[1] / 2;
    float* out = (float*)d_out;

    int* cnt = (int*)d_ws;
    size_t cnt_bytes = ((size_t)N * 4 + 127) & ~(size_t)127;
    u16* w2t = (u16*)((char*)d_ws + cnt_bytes);
    u16* w1t = w2t + (size_t)WNTOT * KP;   // 737280 B after w2t, 16B-aligned

    hipMemsetAsync(out, 0, (size_t)N * 80 * 4, stream);
    hipMemsetAsync(cnt, 0, (size_t)N * 4, stream);

    int prep_total = WNTOT * KP + 128 * 32;
    prep_w<<<(prep_total + 255) / 256, 256, 0, stream>>>(fc_w2, fc_b2, fc_w1, w2t, w1t);
    count_k<<<(E + 255) / 256, 256, 0, stream>>>(edge_index, E, cnt);
    tpcl_main<<<(E + E_TILE - 1) / E_TILE, 256, 0, stream>>>(
        node_attr, edge_index, edge_attr, edge_sh, w1t, fc_b1, w2t, out, N, E);
    finalize_k<<<(N * 80 + 255) / 256, 256, 0, stream>>>(out, cnt, N * 80);
}